// Round 9
// baseline (1463.300 us; speedup 1.0000x reference)
//
#include <hip/hip_runtime.h>

#define D     384
#define E     769      // 1 + 2*D
#define NTOK  4096
#define BPN   32       // B*P
#define NCH   64       // chunks of 64 rows per (b,p)

typedef short s16x8 __attribute__((ext_vector_type(8)));
typedef float f32x4 __attribute__((ext_vector_type(4)));
typedef float f32x2 __attribute__((ext_vector_type(2)));

__device__ __forceinline__ unsigned short f2bf(float f){
  unsigned int u = __builtin_bit_cast(unsigned int, f);
  u += 0x7FFFu + ((u >> 16) & 1u);          // round-to-nearest-even
  return (unsigned short)(u >> 16);
}

// ---------------- K0: pack wq; build FRAGMENT-ORDERED bf16 weights ----------------
// frag idx f = ((ntile*12 + kt)*64 + lane)*8 + pos ; lane = l4*16+l15
// element   = W[k = kt*32 + l4*8 + pos][col = ntile*16 + l15]
__global__ void k0_prep(const float* __restrict__ wqkv, const float* __restrict__ wout,
                        float* __restrict__ wq, unsigned short* __restrict__ wvF,
                        unsigned short* __restrict__ woF){
  int tid = blockIdx.x*256 + threadIdx.x;     // 0 .. 147455
  if (tid < D) wq[tid] = wqkv[(size_t)tid*E];              // w_qkv[:,0]
  if (tid < 24*12*64*8){
    int pos = tid & 7;
    int lane = (tid >> 3) & 63;
    int kt  = (tid >> 9) % 12;
    int nt  = tid / 6144;
    int l15 = lane & 15, l4 = lane >> 4;
    int col = nt*16 + l15;
    int k   = kt*32 + l4*8 + pos;
    wvF[tid] = f2bf(wqkv[(size_t)k*E + 385 + col]);        // wv[k][col]
    woF[tid] = f2bf(wout[(size_t)k*D + col]);              // wout[k][col]
  }
}

// ---------------- kA: fused q + ONLINE chunk-softmax + weighted row-sum ----------------
// per (bp, chunk of 64 rows): 2 sub-tiles of 32 rows staged in LDS fp32;
// online (m,l,acc) update; single global H pass.
__global__ __launch_bounds__(384)
void kA_fused(const float* __restrict__ H, const float* __restrict__ wq,
              float* __restrict__ partial, float* __restrict__ mArr,
              float* __restrict__ lArr){
  __shared__ float Hs[32][D];   // 48 KB
  __shared__ float qs[32];
  const int ch = blockIdx.x, bp = blockIdx.y;
  const int t = threadIdx.x;                 // 384 threads, 6 waves
  const int wave = t >> 6, lane = t & 63;

  float acc = 0.f, mRun = -3.4e38f, lRun = 0.f;

  for (int s = 0; s < 2; ++s){
    if (s) __syncthreads();                  // prev phase-B readers done
    const size_t base = (size_t)bp*NTOK + (size_t)ch*64 + s*32;

    // stage 32 rows + per-row dot with wq
    for (int r = wave; r < 32; r += 6){
      const float* hr = H + (base + r)*D;
      float a = 0.f;
      #pragma unroll
      for (int seg = 0; seg < 3; ++seg){
        int k = lane*2 + seg*128;
        f32x2 h = *reinterpret_cast<const f32x2*>(hr + k);
        f32x2 w = *reinterpret_cast<const f32x2*>(wq + k);
        a += h.x*w.x + h.y*w.y;
        *reinterpret_cast<f32x2*>(&Hs[r][k]) = h;
      }
      #pragma unroll
      for (int off=32; off; off>>=1) a += __shfl_xor(a, off, 64);
      if (lane == 0) qs[r] = a;
    }
    __syncthreads();

    // online update (all threads compute identical m/l; acc is per-column t)
    float msub = qs[0];
    #pragma unroll 8
    for (int n=1;n<32;++n) msub = fmaxf(msub, qs[n]);
    float mNew  = fmaxf(mRun, msub);
    float scale = __expf(mRun - mNew);       // first iter: exp(-inf) = 0
    acc  *= scale;
    lRun *= scale;
    float lsub = 0.f;
    #pragma unroll 4
    for (int n=0;n<32;++n){
      float w = __expf(qs[n] - mNew);
      lsub += w;
      acc  += w * Hs[n][t];
    }
    lRun += lsub;
    mRun  = mNew;
  }

  partial[((size_t)bp*NCH + ch)*D + t] = acc;
  if (t == 0){ mArr[bp*NCH + ch] = mRun; lArr[bp*NCH + ch] = lRun; }
}

// ---------------- kB: combine chunks -> cv[bp][j] ----------------
__global__ void kB_cv(const float* __restrict__ partial, const float* __restrict__ mArr,
                      const float* __restrict__ lArr, const float* __restrict__ wqkv,
                      const float* __restrict__ bqkv, float* __restrict__ cv){
  __shared__ float S[D];
  const int bp = blockIdx.x, t = threadIdx.x;   // 384 threads
  float M = -3.4e38f;
  #pragma unroll 4
  for (int c = 0; c < NCH; ++c) M = fmaxf(M, mArr[bp*NCH + c]);
  float num = 0.f, den = 0.f;
  #pragma unroll 2
  for (int c = 0; c < NCH; ++c){
    float f = __expf(mArr[bp*NCH + c] - M);
    num += f * partial[((size_t)bp*NCH + c)*D + t];
    den += f * lArr[bp*NCH + c];
  }
  S[t] = num / den;
  __syncthreads();
  float acc = bqkv[1 + t];
  #pragma unroll 4
  for (int k = 0; k < D; ++k)
    acc += S[k] * wqkv[(size_t)k*E + 1 + t];
  cv[(size_t)bp*D + t] = acc;
}

// ---------------- K5: 64 rows per block as TWO serial 32-row passes ----------------
// LDS = 24 KB -> 6 blocks/CU; phase-decorrelated blocks keep HBM busy.
#define BM 64

__global__ __launch_bounds__(256, 5)
void k5_main(const float* __restrict__ H, const unsigned short* __restrict__ wvF,
             const unsigned short* __restrict__ woF, const float* __restrict__ cv,
             const float* __restrict__ bqkv, const float* __restrict__ bout,
             float* __restrict__ out){
  __shared__ unsigned short As[32*D];    // 24576 B; A-tile, then R-tile (in place)
  const int bp = blockIdx.y;
  const int m0 = blockIdx.x*BM;
  const size_t rowbase = (size_t)bp*NTOK + m0;
  const float* A = H + rowbase*D;
  const int t = threadIdx.x;
  const int wave = t>>6, lane = t&63;
  const int l15 = lane&15, l4 = lane>>4;
  const int n0 = wave*96;                      // each of 4 waves owns 96 output cols
  const unsigned short* wvW = wvF + (size_t)wave*6*12*512;
  const unsigned short* woW = woF + (size_t)wave*6*12*512;

  // hoisted per-wave column constants
  float bv[6], cvv[6], bo[6];
  #pragma unroll
  for (int n=0;n<6;++n){
    int col = n0 + n*16 + l15;
    bv[n]  = bqkv[385+col];
    cvv[n] = cv[(size_t)bp*D + col];
    bo[n]  = bout[col];
  }

  #pragma unroll 1
  for (int p=0; p<2; ++p){
    if (p) __syncthreads();                    // pass-0 GEMM2 LDS reads done

    // stage 32 H rows (fp32, coalesced) -> bf16 LDS in FRAGMENT order
    #pragma unroll
    for (int i=0;i<12;++i){
      int c = t + i*256;                 // 0..3071 (float4 chunks)
      int idx8 = c >> 1;                 // 0..1535
      int l15v = idx8 & 15;
      int l4v  = (idx8 >> 4) & 3;
      int ktv  = (idx8 >> 6) % 12;
      int mv   = idx8 / 768;             // 0..1
      f32x4 v = *reinterpret_cast<const f32x4*>(
          A + (size_t)(p*32 + mv*16 + l15v)*D + ktv*32 + l4v*8 + (c&1)*4);
      ushort4 b;
      b.x=f2bf(v.x); b.y=f2bf(v.y); b.z=f2bf(v.z); b.w=f2bf(v.w);
      *reinterpret_cast<ushort4*>(&As[c*4]) = b;
    }
    __syncthreads();

    f32x4 acc[2][6] = {};
    // GEMM1: v = A @ wv
    #pragma unroll
    for (int kt=0; kt<12; ++kt){
      s16x8 a[2], b[6];
      #pragma unroll
      for (int m=0;m<2;++m)
        a[m] = *reinterpret_cast<const s16x8*>(&As[((m*12+kt)*64 + lane)*8]);
      #pragma unroll
      for (int n=0;n<6;++n)
        b[n] = *reinterpret_cast<const s16x8*>(&wvW[((size_t)(n*12+kt)*64 + lane)*8]);
      #pragma unroll
      for (int m=0;m<2;++m)
        #pragma unroll
        for (int n=0;n<6;++n)
          acc[m][n] = __builtin_amdgcn_mfma_f32_16x16x32_bf16(a[m], b[n], acc[m][n], 0,0,0);
    }
    __syncthreads();   // GEMM1 reads done before in-place overwrite

    // epilogue1: r = relu(v + bv) * cv  -> bf16 back into As (fragment order)
    #pragma unroll
    for (int n=0;n<6;++n){
      int col  = n0 + n*16 + l15;
      int kt2  = col >> 5;
      int l42  = (col >> 3) & 3;
      int pos2 = col & 7;
      #pragma unroll
      for (int m=0;m<2;++m){
        #pragma unroll
        for (int r=0;r<4;++r){
          int row = l4*4 + r;
          float v = acc[m][n][r] + bv[n];
          v = v > 0.f ? v*cvv[n] : 0.f;
          As[((m*12+kt2)*64 + l42*16 + row)*8 + pos2] = f2bf(v);
        }
      }
    }
    #pragma unroll
    for (int m=0;m<2;++m)
      #pragma unroll
      for (int n=0;n<6;++n)
        acc[m][n] = (f32x4){0.f,0.f,0.f,0.f};
    __syncthreads();

    // GEMM2: out = R @ Wout
    #pragma unroll
    for (int kt=0; kt<12; ++kt){
      s16x8 a[2], b[6];
      #pragma unroll
      for (int m=0;m<2;++m)
        a[m] = *reinterpret_cast<const s16x8*>(&As[((m*12+kt)*64 + lane)*8]);
      #pragma unroll
      for (int n=0;n<6;++n)
        b[n] = *reinterpret_cast<const s16x8*>(&woW[((size_t)(n*12+kt)*64 + lane)*8]);
      #pragma unroll
      for (int m=0;m<2;++m)
        #pragma unroll
        for (int n=0;n<6;++n)
          acc[m][n] = __builtin_amdgcn_mfma_f32_16x16x32_bf16(a[m], b[n], acc[m][n], 0,0,0);
    }

    // direct stores (R2-proven path)
    #pragma unroll
    for (int n=0;n<6;++n){
      int col = n0 + n*16 + l15;
      #pragma unroll
      for (int m=0;m<2;++m)
        #pragma unroll
        for (int r=0;r<4;++r){
          int row = p*32 + m*16 + l4*4 + r;
          out[(rowbase+row)*D + col] = acc[m][n][r] + bo[n];
        }
    }
  }
}

extern "C" void kernel_launch(void* const* d_in, const int* in_sizes, int n_in,
                              void* d_out, int out_size, void* d_ws, size_t ws_size,
                              hipStream_t stream){
  const float* H    = (const float*)d_in[0];
  const float* wqkv = (const float*)d_in[1];
  const float* bqkv = (const float*)d_in[2];
  const float* wout = (const float*)d_in[3];
  const float* bout = (const float*)d_in[4];
  float* out = (float*)d_out;

  char* ws = (char*)d_ws;                              // total usage: 3.63 MB
  float*          partial = (float*)(ws + 0x000000);   // 32*64*384*4 = 3.0 MB
  float*          mArr    = (float*)(ws + 0x300000);   // 8 KB
  float*          lArr    = (float*)(ws + 0x302000);   // 8 KB
  float*          cv      = (float*)(ws + 0x304000);   // 48 KB
  float*          wq      = (float*)(ws + 0x310000);   // 1.5 KB
  unsigned short* wvF     = (unsigned short*)(ws + 0x311000);  // 288 KB
  unsigned short* woF     = (unsigned short*)(ws + 0x359000);  // 288 KB (end 0x3A1000)

  hipLaunchKernelGGL(k0_prep,  dim3(576),          dim3(256), 0, stream, wqkv, wout, wq, wvF, woF);
  hipLaunchKernelGGL(kA_fused, dim3(NCH, BPN),     dim3(384), 0, stream, H, wq, partial, mArr, lArr);
  hipLaunchKernelGGL(kB_cv,    dim3(BPN),          dim3(384), 0, stream, partial, mArr, lArr, wqkv, bqkv, cv);
  hipLaunchKernelGGL(k5_main,  dim3(NTOK/BM, BPN), dim3(256), 0, stream, H, wvF, woF, cv, bqkv, bout, out);
}

// Round 10
// 1351.075 us; speedup vs baseline: 1.0831x; 1.0831x over previous
//
#include <hip/hip_runtime.h>

#define D     384
#define E     769      // 1 + 2*D
#define NTOK  4096
#define BPN   32       // B*P
#define NCH   64       // chunks of 64 rows per (b,p)

typedef short s16x8 __attribute__((ext_vector_type(8)));
typedef float f32x4 __attribute__((ext_vector_type(4)));
typedef float f32x2 __attribute__((ext_vector_type(2)));

__device__ __forceinline__ unsigned short f2bf(float f){
  unsigned int u = __builtin_bit_cast(unsigned int, f);
  u += 0x7FFFu + ((u >> 16) & 1u);          // round-to-nearest-even
  return (unsigned short)(u >> 16);
}

// ---------------- K0: pack wq; build FRAGMENT-ORDERED bf16 weights ----------------
// frag idx f = ((ntile*12 + kt)*64 + lane)*8 + pos ; lane = l4*16+l15
// element   = W[k = kt*32 + l4*8 + pos][col = ntile*16 + l15]
__global__ void k0_prep(const float* __restrict__ wqkv, const float* __restrict__ wout,
                        float* __restrict__ wq, unsigned short* __restrict__ wvF,
                        unsigned short* __restrict__ woF){
  int tid = blockIdx.x*256 + threadIdx.x;     // 0 .. 147455
  if (tid < D) wq[tid] = wqkv[(size_t)tid*E];              // w_qkv[:,0]
  if (tid < 24*12*64*8){
    int pos = tid & 7;
    int lane = (tid >> 3) & 63;
    int kt  = (tid >> 9) % 12;
    int nt  = tid / 6144;
    int l15 = lane & 15, l4 = lane >> 4;
    int col = nt*16 + l15;
    int k   = kt*32 + l4*8 + pos;
    wvF[tid] = f2bf(wqkv[(size_t)k*E + 385 + col]);        // wv[k][col]
    woF[tid] = f2bf(wout[(size_t)k*D + col]);              // wout[k][col]
  }
}

// ---------------- kA: fused q + ONLINE chunk-softmax + weighted row-sum ----------------
// per (bp, chunk of 64 rows): 2 sub-tiles of 32 rows staged in LDS fp32;
// online (m,l,acc) update; single global H pass.
__global__ __launch_bounds__(384)
void kA_fused(const float* __restrict__ H, const float* __restrict__ wq,
              float* __restrict__ partial, float* __restrict__ mArr,
              float* __restrict__ lArr){
  __shared__ float Hs[32][D];   // 48 KB
  __shared__ float qs[32];
  const int ch = blockIdx.x, bp = blockIdx.y;
  const int t = threadIdx.x;                 // 384 threads, 6 waves
  const int wave = t >> 6, lane = t & 63;

  float acc = 0.f, mRun = -3.4e38f, lRun = 0.f;

  for (int s = 0; s < 2; ++s){
    if (s) __syncthreads();                  // prev phase-B readers done
    const size_t base = (size_t)bp*NTOK + (size_t)ch*64 + s*32;

    // stage 32 rows + per-row dot with wq
    for (int r = wave; r < 32; r += 6){
      const float* hr = H + (base + r)*D;
      float a = 0.f;
      #pragma unroll
      for (int seg = 0; seg < 3; ++seg){
        int k = lane*2 + seg*128;
        f32x2 h = *reinterpret_cast<const f32x2*>(hr + k);
        f32x2 w = *reinterpret_cast<const f32x2*>(wq + k);
        a += h.x*w.x + h.y*w.y;
        *reinterpret_cast<f32x2*>(&Hs[r][k]) = h;
      }
      #pragma unroll
      for (int off=32; off; off>>=1) a += __shfl_xor(a, off, 64);
      if (lane == 0) qs[r] = a;
    }
    __syncthreads();

    // online update (all threads compute identical m/l; acc is per-column t)
    float msub = qs[0];
    #pragma unroll 8
    for (int n=1;n<32;++n) msub = fmaxf(msub, qs[n]);
    float mNew  = fmaxf(mRun, msub);
    float scale = __expf(mRun - mNew);       // first iter: exp(-inf) = 0
    acc  *= scale;
    lRun *= scale;
    float lsub = 0.f;
    #pragma unroll 4
    for (int n=0;n<32;++n){
      float w = __expf(qs[n] - mNew);
      lsub += w;
      acc  += w * Hs[n][t];
    }
    lRun += lsub;
    mRun  = mNew;
  }

  partial[((size_t)bp*NCH + ch)*D + t] = acc;
  if (t == 0){ mArr[bp*NCH + ch] = mRun; lArr[bp*NCH + ch] = lRun; }
}

// ---------------- kB: combine chunks -> cv[bp][j] ----------------
__global__ void kB_cv(const float* __restrict__ partial, const float* __restrict__ mArr,
                      const float* __restrict__ lArr, const float* __restrict__ wqkv,
                      const float* __restrict__ bqkv, float* __restrict__ cv){
  __shared__ float S[D];
  const int bp = blockIdx.x, t = threadIdx.x;   // 384 threads
  float M = -3.4e38f;
  #pragma unroll 4
  for (int c = 0; c < NCH; ++c) M = fmaxf(M, mArr[bp*NCH + c]);
  float num = 0.f, den = 0.f;
  #pragma unroll 2
  for (int c = 0; c < NCH; ++c){
    float f = __expf(mArr[bp*NCH + c] - M);
    num += f * partial[((size_t)bp*NCH + c)*D + t];
    den += f * lArr[bp*NCH + c];
  }
  S[t] = num / den;
  __syncthreads();
  float acc = bqkv[1 + t];
  #pragma unroll 4
  for (int k = 0; k < D; ++k)
    acc += S[k] * wqkv[(size_t)k*E + 1 + t];
  cv[(size_t)bp*D + t] = acc;
}

// ---------------- K5: 64 rows per block as TWO serial 32-row passes ----------------
// LDS = 24 KB -> 6 blocks/CU; NOTE: launch_bounds arg2 must stay <=3 —
// (256,5) capped VGPR at 48 and spilled ~3 GB of scratch traffic (R9).
#define BM 64

__global__ __launch_bounds__(256, 3)
void k5_main(const float* __restrict__ H, const unsigned short* __restrict__ wvF,
             const unsigned short* __restrict__ woF, const float* __restrict__ cv,
             const float* __restrict__ bqkv, const float* __restrict__ bout,
             float* __restrict__ out){
  __shared__ unsigned short As[32*D];    // 24576 B; A-tile, then R-tile (in place)
  const int bp = blockIdx.y;
  const int m0 = blockIdx.x*BM;
  const size_t rowbase = (size_t)bp*NTOK + m0;
  const float* A = H + rowbase*D;
  const int t = threadIdx.x;
  const int wave = t>>6, lane = t&63;
  const int l15 = lane&15, l4 = lane>>4;
  const int n0 = wave*96;                      // each of 4 waves owns 96 output cols
  const unsigned short* wvW = wvF + (size_t)wave*6*12*512;
  const unsigned short* woW = woF + (size_t)wave*6*12*512;

  // hoisted per-wave column constants
  float bv[6], cvv[6], bo[6];
  #pragma unroll
  for (int n=0;n<6;++n){
    int col = n0 + n*16 + l15;
    bv[n]  = bqkv[385+col];
    cvv[n] = cv[(size_t)bp*D + col];
    bo[n]  = bout[col];
  }

  #pragma unroll 1
  for (int p=0; p<2; ++p){
    if (p) __syncthreads();                    // pass-0 GEMM2 LDS reads done

    // stage 32 H rows (fp32, coalesced) -> bf16 LDS in FRAGMENT order
    #pragma unroll
    for (int i=0;i<12;++i){
      int c = t + i*256;                 // 0..3071 (float4 chunks)
      int idx8 = c >> 1;                 // 0..1535
      int l15v = idx8 & 15;
      int l4v  = (idx8 >> 4) & 3;
      int ktv  = (idx8 >> 6) % 12;
      int mv   = idx8 / 768;             // 0..1
      f32x4 v = *reinterpret_cast<const f32x4*>(
          A + (size_t)(p*32 + mv*16 + l15v)*D + ktv*32 + l4v*8 + (c&1)*4);
      ushort4 b;
      b.x=f2bf(v.x); b.y=f2bf(v.y); b.z=f2bf(v.z); b.w=f2bf(v.w);
      *reinterpret_cast<ushort4*>(&As[c*4]) = b;
    }
    __syncthreads();

    f32x4 acc[2][6] = {};
    // GEMM1: v = A @ wv
    #pragma unroll
    for (int kt=0; kt<12; ++kt){
      s16x8 a[2], b[6];
      #pragma unroll
      for (int m=0;m<2;++m)
        a[m] = *reinterpret_cast<const s16x8*>(&As[((m*12+kt)*64 + lane)*8]);
      #pragma unroll
      for (int n=0;n<6;++n)
        b[n] = *reinterpret_cast<const s16x8*>(&wvW[((size_t)(n*12+kt)*64 + lane)*8]);
      #pragma unroll
      for (int m=0;m<2;++m)
        #pragma unroll
        for (int n=0;n<6;++n)
          acc[m][n] = __builtin_amdgcn_mfma_f32_16x16x32_bf16(a[m], b[n], acc[m][n], 0,0,0);
    }
    __syncthreads();   // GEMM1 reads done before in-place overwrite

    // epilogue1: r = relu(v + bv) * cv  -> bf16 back into As (fragment order)
    #pragma unroll
    for (int n=0;n<6;++n){
      int col  = n0 + n*16 + l15;
      int kt2  = col >> 5;
      int l42  = (col >> 3) & 3;
      int pos2 = col & 7;
      #pragma unroll
      for (int m=0;m<2;++m){
        #pragma unroll
        for (int r=0;r<4;++r){
          int row = l4*4 + r;
          float v = acc[m][n][r] + bv[n];
          v = v > 0.f ? v*cvv[n] : 0.f;
          As[((m*12+kt2)*64 + l42*16 + row)*8 + pos2] = f2bf(v);
        }
      }
    }
    #pragma unroll
    for (int m=0;m<2;++m)
      #pragma unroll
      for (int n=0;n<6;++n)
        acc[m][n] = (f32x4){0.f,0.f,0.f,0.f};
    __syncthreads();

    // GEMM2: out = R @ Wout
    #pragma unroll
    for (int kt=0; kt<12; ++kt){
      s16x8 a[2], b[6];
      #pragma unroll
      for (int m=0;m<2;++m)
        a[m] = *reinterpret_cast<const s16x8*>(&As[((m*12+kt)*64 + lane)*8]);
      #pragma unroll
      for (int n=0;n<6;++n)
        b[n] = *reinterpret_cast<const s16x8*>(&woW[((size_t)(n*12+kt)*64 + lane)*8]);
      #pragma unroll
      for (int m=0;m<2;++m)
        #pragma unroll
        for (int n=0;n<6;++n)
          acc[m][n] = __builtin_amdgcn_mfma_f32_16x16x32_bf16(a[m], b[n], acc[m][n], 0,0,0);
    }

    // direct stores (R2-proven path)
    #pragma unroll
    for (int n=0;n<6;++n){
      int col = n0 + n*16 + l15;
      #pragma unroll
      for (int m=0;m<2;++m)
        #pragma unroll
        for (int r=0;r<4;++r){
          int row = p*32 + m*16 + l4*4 + r;
          out[(rowbase+row)*D + col] = acc[m][n][r] + bo[n];
        }
    }
  }
}

extern "C" void kernel_launch(void* const* d_in, const int* in_sizes, int n_in,
                              void* d_out, int out_size, void* d_ws, size_t ws_size,
                              hipStream_t stream){
  const float* H    = (const float*)d_in[0];
  const float* wqkv = (const float*)d_in[1];
  const float* bqkv = (const float*)d_in[2];
  const float* wout = (const float*)d_in[3];
  const float* bout = (const float*)d_in[4];
  float* out = (float*)d_out;

  char* ws = (char*)d_ws;                              // total usage: 3.63 MB
  float*          partial = (float*)(ws + 0x000000);   // 32*64*384*4 = 3.0 MB
  float*          mArr    = (float*)(ws + 0x300000);   // 8 KB
  float*          lArr    = (float*)(ws + 0x302000);   // 8 KB
  float*          cv      = (float*)(ws + 0x304000);   // 48 KB
  float*          wq      = (float*)(ws + 0x310000);   // 1.5 KB
  unsigned short* wvF     = (unsigned short*)(ws + 0x311000);  // 288 KB
  unsigned short* woF     = (unsigned short*)(ws + 0x359000);  // 288 KB (end 0x3A1000)

  hipLaunchKernelGGL(k0_prep,  dim3(576),          dim3(256), 0, stream, wqkv, wout, wq, wvF, woF);
  hipLaunchKernelGGL(kA_fused, dim3(NCH, BPN),     dim3(384), 0, stream, H, wq, partial, mArr, lArr);
  hipLaunchKernelGGL(kB_cv,    dim3(BPN),          dim3(384), 0, stream, partial, mArr, lArr, wqkv, bqkv, cv);
  hipLaunchKernelGGL(k5_main,  dim3(NTOK/BM, BPN), dim3(256), 0, stream, H, wvF, woF, cv, bqkv, bout, out);
}

// Round 11
// 311.543 us; speedup vs baseline: 4.6969x; 4.3367x over previous
//
#include <hip/hip_runtime.h>

#define D     384
#define E     769      // 1 + 2*D
#define NTOK  4096
#define BPN   32       // B*P
#define NCH   32       // chunks of 128 rows per (b,p)

typedef short s16x8 __attribute__((ext_vector_type(8)));
typedef float f32x4 __attribute__((ext_vector_type(4)));
typedef float f32x2 __attribute__((ext_vector_type(2)));

__device__ __forceinline__ unsigned short f2bf(float f){
  unsigned int u = __builtin_bit_cast(unsigned int, f);
  u += 0x7FFFu + ((u >> 16) & 1u);          // round-to-nearest-even
  return (unsigned short)(u >> 16);
}

// ---------------- K0: pack wq; build FRAGMENT-ORDERED bf16 weights ----------------
// frag idx f = ((ntile*12 + kt)*64 + lane)*8 + pos ; lane = l4*16+l15
// element   = W[k = kt*32 + l4*8 + pos][col = ntile*16 + l15]
__global__ void k0_prep(const float* __restrict__ wqkv, const float* __restrict__ wout,
                        float* __restrict__ wq, unsigned short* __restrict__ wvF,
                        unsigned short* __restrict__ woF){
  int tid = blockIdx.x*256 + threadIdx.x;     // 0 .. 147455
  if (tid < D) wq[tid] = wqkv[(size_t)tid*E];              // w_qkv[:,0]
  if (tid < 24*12*64*8){
    int pos = tid & 7;
    int lane = (tid >> 3) & 63;
    int kt  = (tid >> 9) % 12;
    int nt  = tid / 6144;
    int l15 = lane & 15, l4 = lane >> 4;
    int col = nt*16 + l15;
    int k   = kt*32 + l4*8 + pos;
    wvF[tid] = f2bf(wqkv[(size_t)k*E + 385 + col]);        // wv[k][col]
    woF[tid] = f2bf(wout[(size_t)k*D + col]);              // wout[k][col]
  }
}

// ---------------- kA: fused q + ONLINE chunk-softmax + weighted row-sum (R5-exact) --
// per (bp, chunk of 128 rows): 4 sub-tiles of 32 rows staged in LDS fp32;
// online (m,l,acc) update; single global H pass.
__global__ __launch_bounds__(384)
void kA_fused(const float* __restrict__ H, const float* __restrict__ wq,
              float* __restrict__ partial, float* __restrict__ mArr,
              float* __restrict__ lArr){
  __shared__ float Hs[32][D];   // 48 KB
  __shared__ float qs[32];
  const int ch = blockIdx.x, bp = blockIdx.y;
  const int t = threadIdx.x;                 // 384 threads, 6 waves
  const int wave = t >> 6, lane = t & 63;

  float acc = 0.f, mRun = -3.4e38f, lRun = 0.f;

  for (int s = 0; s < 4; ++s){
    if (s) __syncthreads();                  // prev phase-B readers done
    const size_t base = (size_t)bp*NTOK + (size_t)ch*128 + s*32;

    // stage 32 rows (nt, single touch) + per-row dot with wq
    for (int r = wave; r < 32; r += 6){
      const float* hr = H + (base + r)*D;
      float a = 0.f;
      #pragma unroll
      for (int seg = 0; seg < 3; ++seg){
        int k = lane*2 + seg*128;
        f32x2 h = __builtin_nontemporal_load(reinterpret_cast<const f32x2*>(hr + k));
        f32x2 w = *reinterpret_cast<const f32x2*>(wq + k);
        a += h.x*w.x + h.y*w.y;
        *reinterpret_cast<f32x2*>(&Hs[r][k]) = h;
      }
      #pragma unroll
      for (int off=32; off; off>>=1) a += __shfl_xor(a, off, 64);
      if (lane == 0) qs[r] = a;
    }
    __syncthreads();

    // online update (all threads compute identical m/l; acc is per-column t)
    float msub = qs[0];
    #pragma unroll 8
    for (int n=1;n<32;++n) msub = fmaxf(msub, qs[n]);
    float mNew  = fmaxf(mRun, msub);
    float scale = __expf(mRun - mNew);       // first iter: exp(-inf) = 0
    acc  *= scale;
    lRun *= scale;
    float lsub = 0.f;
    #pragma unroll 4
    for (int n=0;n<32;++n){
      float w = __expf(qs[n] - mNew);
      lsub += w;
      acc  += w * Hs[n][t];
    }
    lRun += lsub;
    mRun  = mNew;
  }

  partial[((size_t)bp*NCH + ch)*D + t] = acc;
  if (t == 0){ mArr[bp*NCH + ch] = mRun; lArr[bp*NCH + ch] = lRun; }
}

// ---------------- kB: combine chunks -> cv[bp][j] ----------------
__global__ void kB_cv(const float* __restrict__ partial, const float* __restrict__ mArr,
                      const float* __restrict__ lArr, const float* __restrict__ wqkv,
                      const float* __restrict__ bqkv, float* __restrict__ cv){
  __shared__ float S[D];
  const int bp = blockIdx.x, t = threadIdx.x;   // 384 threads
  float M = -3.4e38f;
  #pragma unroll 4
  for (int c = 0; c < NCH; ++c) M = fmaxf(M, mArr[bp*NCH + c]);
  float num = 0.f, den = 0.f;
  #pragma unroll 2
  for (int c = 0; c < NCH; ++c){
    float f = __expf(mArr[bp*NCH + c] - M);
    num += f * partial[((size_t)bp*NCH + c)*D + t];
    den += f * lArr[bp*NCH + c];
  }
  S[t] = num / den;
  __syncthreads();
  float acc = bqkv[1 + t];
  #pragma unroll 4
  for (int k = 0; k < D; ++k)
    acc += S[k] * wqkv[(size_t)k*E + 1 + t];
  cv[(size_t)bp*D + t] = acc;
}

// ---------------- K5: one-pass BM=64, 8 waves (2 m-groups x 4 n-groups) ----------------
// Halved per-thread accumulator state (acc[2][6]) -> more blocks/CU than the
// 4-wave acc[4][6] version (reg-file was the occupancy cap, not LDS).
// NOTE: never cap regs via launch_bounds arg2 (R9: (256,5)->48 VGPR->~3GB spill traffic).
#define BM 64

__global__ __launch_bounds__(512, 2)
void k5_main(const float* __restrict__ H, const unsigned short* __restrict__ wvF,
             const unsigned short* __restrict__ woF, const float* __restrict__ cv,
             const float* __restrict__ bqkv, const float* __restrict__ bout,
             float* __restrict__ out){
  __shared__ unsigned short As[BM*D];    // 49152 B; A-tile, then R-tile (in place)
  const int bp = blockIdx.y;
  const int m0 = blockIdx.x*BM;
  const size_t rowbase = (size_t)bp*NTOK + m0;
  const float* A = H + rowbase*D;
  const int t = threadIdx.x;
  const int wave = t>>6, lane = t&63;
  const int l15 = lane&15, l4 = lane>>4;
  const int wm = wave>>2, wn = wave&3;         // 2 m-groups x 4 n-groups
  const int n0 = wn*96;                        // each n-group owns 96 output cols
  const unsigned short* wvW = wvF + (size_t)wn*6*12*512;
  const unsigned short* woW = woF + (size_t)wn*6*12*512;

  // hoisted per-wave column constants
  float bv[6], cvv[6], bo[6];
  #pragma unroll
  for (int n=0;n<6;++n){
    int col = n0 + n*16 + l15;
    bv[n]  = bqkv[385+col];
    cvv[n] = cv[(size_t)bp*D + col];
    bo[n]  = bout[col];
  }

  // stage 64 H rows (fp32, plain, coalesced) -> bf16 LDS in FRAGMENT order
  #pragma unroll
  for (int i=0;i<12;++i){
    int c = t + i*512;                   // 0..6143 (float4 chunks)
    int idx8 = c >> 1;
    int l15v = idx8 & 15;
    int l4v  = (idx8 >> 4) & 3;
    int ktv  = (idx8 >> 6) % 12;
    int mv   = idx8 / 768;
    f32x4 v = *reinterpret_cast<const f32x4*>(
        A + (size_t)(mv*16 + l15v)*D + ktv*32 + l4v*8 + (c&1)*4);
    ushort4 b;
    b.x=f2bf(v.x); b.y=f2bf(v.y); b.z=f2bf(v.z); b.w=f2bf(v.w);
    *reinterpret_cast<ushort4*>(&As[c*4]) = b;
  }
  __syncthreads();

  f32x4 acc[2][6] = {};
  // GEMM1: v = A @ wv   (this wave: m-tiles {wm*2, wm*2+1}, n-tiles wn*6..wn*6+5)
  #pragma unroll
  for (int kt=0; kt<12; ++kt){
    s16x8 a[2], b[6];
    #pragma unroll
    for (int m=0;m<2;++m)
      a[m] = *reinterpret_cast<const s16x8*>(&As[(((wm*2+m)*12+kt)*64 + lane)*8]);
    #pragma unroll
    for (int n=0;n<6;++n)
      b[n] = *reinterpret_cast<const s16x8*>(&wvW[((size_t)(n*12+kt)*64 + lane)*8]);
    #pragma unroll
    for (int m=0;m<2;++m)
      #pragma unroll
      for (int n=0;n<6;++n)
        acc[m][n] = __builtin_amdgcn_mfma_f32_16x16x32_bf16(a[m], b[n], acc[m][n], 0,0,0);
  }
  __syncthreads();   // everyone done reading As before overwrite

  // epilogue1: r = relu(v + bv) * cv  -> bf16 back into As in FRAGMENT order
  // wave (wm,wn) writes (mm = wm*2+m, kt2 in [wn*3, wn*3+2]) cells -> disjoint.
  #pragma unroll
  for (int n=0;n<6;++n){
    int col  = n0 + n*16 + l15;
    int kt2  = col >> 5;
    int l42  = (col >> 3) & 3;
    int pos2 = col & 7;
    #pragma unroll
    for (int m=0;m<2;++m){
      #pragma unroll
      for (int r=0;r<4;++r){
        int row = l4*4 + r;
        float v = acc[m][n][r] + bv[n];
        v = v > 0.f ? v*cvv[n] : 0.f;
        As[(((wm*2+m)*12+kt2)*64 + l42*16 + row)*8 + pos2] = f2bf(v);
      }
    }
  }
  #pragma unroll
  for (int m=0;m<2;++m)
    #pragma unroll
    for (int n=0;n<6;++n)
      acc[m][n] = (f32x4){0.f,0.f,0.f,0.f};
  __syncthreads();

  // GEMM2: out = R @ Wout
  #pragma unroll
  for (int kt=0; kt<12; ++kt){
    s16x8 a[2], b[6];
    #pragma unroll
    for (int m=0;m<2;++m)
      a[m] = *reinterpret_cast<const s16x8*>(&As[(((wm*2+m)*12+kt)*64 + lane)*8]);
    #pragma unroll
    for (int n=0;n<6;++n)
      b[n] = *reinterpret_cast<const s16x8*>(&woW[((size_t)(n*12+kt)*64 + lane)*8]);
    #pragma unroll
    for (int m=0;m<2;++m)
      #pragma unroll
      for (int n=0;n<6;++n)
        acc[m][n] = __builtin_amdgcn_mfma_f32_16x16x32_bf16(a[m], b[n], acc[m][n], 0,0,0);
  }

  // direct stores (R2-proven path)
  #pragma unroll
  for (int n=0;n<6;++n){
    int col = n0 + n*16 + l15;
    #pragma unroll
    for (int m=0;m<2;++m)
      #pragma unroll
      for (int r=0;r<4;++r){
        int row = (wm*2+m)*16 + l4*4 + r;
        out[(rowbase+row)*D + col] = acc[m][n][r] + bo[n];
      }
  }
}

extern "C" void kernel_launch(void* const* d_in, const int* in_sizes, int n_in,
                              void* d_out, int out_size, void* d_ws, size_t ws_size,
                              hipStream_t stream){
  const float* H    = (const float*)d_in[0];
  const float* wqkv = (const float*)d_in[1];
  const float* bqkv = (const float*)d_in[2];
  const float* wout = (const float*)d_in[3];
  const float* bout = (const float*)d_in[4];
  float* out = (float*)d_out;

  char* ws = (char*)d_ws;                              // total usage: 2.13 MB
  float*          partial = (float*)(ws + 0x000000);   // 32*32*384*4 = 1.5 MB
  float*          mArr    = (float*)(ws + 0x180000);   // 4 KB
  float*          lArr    = (float*)(ws + 0x181000);   // 4 KB
  float*          cv      = (float*)(ws + 0x182000);   // 48 KB
  float*          wq      = (float*)(ws + 0x18E000);   // 1.5 KB
  unsigned short* wvF     = (unsigned short*)(ws + 0x190000);  // 288 KB
  unsigned short* woF     = (unsigned short*)(ws + 0x1D8000);  // 288 KB (end 0x220000)

  hipLaunchKernelGGL(k0_prep,  dim3(576),          dim3(256), 0, stream, wqkv, wout, wq, wvF, woF);
  hipLaunchKernelGGL(kA_fused, dim3(NCH, BPN),     dim3(384), 0, stream, H, wq, partial, mArr, lArr);
  hipLaunchKernelGGL(kB_cv,    dim3(BPN),          dim3(384), 0, stream, partial, mArr, lArr, wqkv, bqkv, cv);
  hipLaunchKernelGGL(k5_main,  dim3(NTOK/BM, BPN), dim3(512), 0, stream, H, wvF, woF, cv, bqkv, bout, out);
}